// Round 1
// baseline (201.543 us; speedup 1.0000x reference)
//
#include <hip/hip_runtime.h>
#include <hip/hip_bf16.h>

#define B_ 2
#define S_ 2048
#define D_ 1024
#define H_ 16

typedef __bf16 bf16x8 __attribute__((ext_vector_type(8)));
typedef float f32x4 __attribute__((ext_vector_type(4)));

__device__ __forceinline__ unsigned short f2bf(float f) {
  unsigned int u = __float_as_uint(f);
  u += 0x7fff + ((u >> 16) & 1);   // RNE
  return (unsigned short)(u >> 16);
}

__device__ __forceinline__ void gload_lds16(const void* g, void* l) {
  __builtin_amdgcn_global_load_lds(
      (const __attribute__((address_space(1))) void*)g,
      (__attribute__((address_space(3))) void*)l, 16, 0, 0);
}

// ---------------- fp32 -> bf16 conversion ----------------
__global__ __launch_bounds__(256) void cvt_qkv(
    const float* __restrict__ a, const float* __restrict__ b, const float* __restrict__ c,
    unsigned short* __restrict__ da, unsigned short* __restrict__ db,
    unsigned short* __restrict__ dc, int n4) {
  const int z = blockIdx.z;
  const float* s = z == 0 ? a : (z == 1 ? b : c);
  unsigned short* d = z == 0 ? da : (z == 1 ? db : dc);
  int stride = gridDim.x * blockDim.x;
  for (int i = blockIdx.x * blockDim.x + threadIdx.x; i < n4; i += stride) {
    float4 f = ((const float4*)s)[i];
    ushort4 o;
    o.x = f2bf(f.x); o.y = f2bf(f.y); o.z = f2bf(f.z); o.w = f2bf(f.w);
    ((ushort4*)d)[i] = o;
  }
}

__global__ __launch_bounds__(256) void cvt_w(
    const float* __restrict__ a, const float* __restrict__ b,
    const float* __restrict__ c, const float* __restrict__ d,
    unsigned short* __restrict__ da, unsigned short* __restrict__ db,
    unsigned short* __restrict__ dc, unsigned short* __restrict__ dd, int n4) {
  const int z = blockIdx.z;
  const float* s = z == 0 ? a : (z == 1 ? b : (z == 2 ? c : d));
  unsigned short* o = z == 0 ? da : (z == 1 ? db : (z == 2 ? dc : dd));
  int stride = gridDim.x * blockDim.x;
  for (int i = blockIdx.x * blockDim.x + threadIdx.x; i < n4; i += stride) {
    float4 f = ((const float4*)s)[i];
    ushort4 u;
    u.x = f2bf(f.x); u.y = f2bf(f.y); u.z = f2bf(f.z); u.w = f2bf(f.w);
    ((ushort4*)o)[i] = u;
  }
}

// ---------------- mask all-ones check ----------------
__global__ __launch_bounds__(256) void mask_check(const int* __restrict__ m,
                                                  int* __restrict__ flag, int n4) {
  int stride = gridDim.x * blockDim.x;
  bool z = false;
  for (int i = blockIdx.x * blockDim.x + threadIdx.x; i < n4; i += stride) {
    int4 v = ((const int4*)m)[i];
    z |= (v.x == 0) || (v.y == 0) || (v.z == 0) || (v.w == 0);
  }
  if (__any(z)) {
    if ((threadIdx.x & 63) == 0) atomicOr(flag, 1);
  }
}

// ---------------- 128x128 bf16 GEMM core (m97 structure) ----------------
// y[i][n] = sum_k A[i][k] * W[n][k]  (NT: W row-major [N][K] is B^T)
__device__ __forceinline__ void gemm_core(
    const unsigned short* __restrict__ A, const unsigned short* __restrict__ W,
    unsigned short* As, unsigned short* Bs, int rowBase, int colBase,
    f32x4 (&acc)[4][4]) {
  const int tid = threadIdx.x, lane = tid & 63, w = tid >> 6;
  const int wm = w >> 1, wn = w & 1, l15 = lane & 15, l4 = lane >> 4;
  for (int kt = 0; kt < 16; ++kt) {
    // stage A[128][64], B[128][64] via global_load_lds, XOR-swizzled source
#pragma unroll
    for (int i = 0; i < 4; i++) {
      int chunk = (w * 4 + i) * 64 + lane;
      int row = chunk >> 3, c = chunk & 7;
      int cs = c ^ (row & 7);
      gload_lds16(A + (size_t)(rowBase + row) * 1024 + kt * 64 + cs * 8,
                  (char*)As + (w * 4 + i) * 1024);
      gload_lds16(W + (size_t)(colBase + row) * 1024 + kt * 64 + cs * 8,
                  (char*)Bs + (w * 4 + i) * 1024);
    }
    __syncthreads();
#pragma unroll
    for (int ks = 0; ks < 2; ks++) {
      bf16x8 af[4], bfr[4];
#pragma unroll
      for (int mi = 0; mi < 4; mi++) {
        int row = wm * 64 + mi * 16 + l15;
        af[mi] = *(const bf16x8*)((const char*)As + row * 128 +
                                  (((ks * 4 + l4) ^ (row & 7)) << 4));
      }
#pragma unroll
      for (int ni = 0; ni < 4; ni++) {
        int row = wn * 64 + ni * 16 + l15;
        bfr[ni] = *(const bf16x8*)((const char*)Bs + row * 128 +
                                   (((ks * 4 + l4) ^ (row & 7)) << 4));
      }
#pragma unroll
      for (int mi = 0; mi < 4; mi++)
#pragma unroll
        for (int ni = 0; ni < 4; ni++)
          acc[mi][ni] = __builtin_amdgcn_mfma_f32_16x16x32_bf16(
              af[mi], bfr[ni], acc[mi][ni], 0, 0, 0);
    }
    __syncthreads();
  }
}

// Q/K/V projections in one launch (grid.z selects). Q pre-scaled by 0.125.
// Q,K stored [B,H,S,64]; V stored transposed [B,H,64,S].
__global__ __launch_bounds__(256, 2) void gemm_qkv(
    const unsigned short* __restrict__ qA, const unsigned short* __restrict__ kA,
    const unsigned short* __restrict__ vA,
    const unsigned short* __restrict__ Wq, const unsigned short* __restrict__ Wk,
    const unsigned short* __restrict__ Wv,
    unsigned short* __restrict__ Qp, unsigned short* __restrict__ Kp,
    unsigned short* __restrict__ Vtp) {
  __shared__ unsigned short As[128 * 64], Bs[128 * 64];
  const int z = blockIdx.z;
  const unsigned short* A = z == 0 ? qA : (z == 1 ? kA : vA);
  const unsigned short* W = z == 0 ? Wq : (z == 1 ? Wk : Wv);
  const int rowBase = blockIdx.y * 128, colBase = blockIdx.x * 128;
  f32x4 acc[4][4] = {};
  gemm_core(A, W, As, Bs, rowBase, colBase, acc);
  const int tid = threadIdx.x, lane = tid & 63, w = tid >> 6;
  const int wm = w >> 1, wn = w & 1, l15 = lane & 15, l4 = lane >> 4;
#pragma unroll
  for (int mi = 0; mi < 4; mi++)
#pragma unroll
    for (int ni = 0; ni < 4; ni++)
#pragma unroll
      for (int r = 0; r < 4; r++) {
        int gr = rowBase + wm * 64 + mi * 16 + l4 * 4 + r;  // b*S + s
        int gc = colBase + wn * 64 + ni * 16 + l15;         // h*64 + d
        int b = gr >> 11, s = gr & 2047, h = gc >> 6, d = gc & 63;
        float v = acc[mi][ni][r];
        if (z == 0)
          Qp[(((size_t)(b * 16 + h) * 2048 + s) << 6) + d] = f2bf(v * 0.125f);
        else if (z == 1)
          Kp[(((size_t)(b * 16 + h) * 2048 + s) << 6) + d] = f2bf(v);
        else
          Vtp[((size_t)(b * 16 + h) * 64 + d) * 2048 + s] = f2bf(v);
      }
}

// Output projection -> fp32 d_out
__global__ __launch_bounds__(256, 2) void gemm_o(
    const unsigned short* __restrict__ A, const unsigned short* __restrict__ W,
    float* __restrict__ Out) {
  __shared__ unsigned short As[128 * 64], Bs[128 * 64];
  const int rowBase = blockIdx.y * 128, colBase = blockIdx.x * 128;
  f32x4 acc[4][4] = {};
  gemm_core(A, W, As, Bs, rowBase, colBase, acc);
  const int tid = threadIdx.x, lane = tid & 63, w = tid >> 6;
  const int wm = w >> 1, wn = w & 1, l15 = lane & 15, l4 = lane >> 4;
#pragma unroll
  for (int mi = 0; mi < 4; mi++)
#pragma unroll
    for (int ni = 0; ni < 4; ni++)
#pragma unroll
      for (int r = 0; r < 4; r++) {
        int gr = rowBase + wm * 64 + mi * 16 + l4 * 4 + r;
        int gc = colBase + wn * 64 + ni * 16 + l15;
        Out[(size_t)gr * 1024 + gc] = acc[mi][ni][r];
      }
}

// ---------------- flash attention ----------------
// grid (S/128, H, B), 256 threads = 4 waves, wave owns 32 q rows.
__global__ __launch_bounds__(256, 2) void attn(
    const unsigned short* __restrict__ Qp, const unsigned short* __restrict__ Kp,
    const unsigned short* __restrict__ Vt, unsigned short* __restrict__ Xo,
    const int* __restrict__ flag, const int* __restrict__ mask) {
  __shared__ unsigned short Ks[64 * 64];
  __shared__ unsigned short Vs[64 * 64];
  __shared__ unsigned short Pl[4][32][72];  // pad 64->72: stride 144B, conflict-free b128
  const int tid = threadIdx.x, lane = tid & 63, w = tid >> 6;
  const int l15 = lane & 15, l4 = lane >> 4;
  const int h = blockIdx.y, b = blockIdx.z;
  const int bh = b * H_ + h;
  const int q0 = blockIdx.x * 128 + w * 32;
  const int hz = *flag;

  bf16x8 qf[2][2];
#pragma unroll
  for (int qb = 0; qb < 2; qb++)
#pragma unroll
    for (int ks = 0; ks < 2; ks++)
      qf[qb][ks] = *(const bf16x8*)(Qp + ((size_t)bh * S_ + q0 + qb * 16 + l15) * 64 +
                                    ks * 32 + l4 * 8);

  float mstate[8], lstate[8];
#pragma unroll
  for (int i = 0; i < 8; i++) { mstate[i] = -__builtin_inff(); lstate[i] = 0.f; }
  f32x4 accO[2][4] = {};

  for (int kt = 0; kt < 32; ++kt) {
    // stage K tile [64 kpos][64 d] and Vt tile [64 d][64 kpos], swizzled source
#pragma unroll
    for (int i = 0; i < 2; i++) {
      int chunk = (w * 2 + i) * 64 + lane;
      int row = chunk >> 3, c = chunk & 7;
      int cs = c ^ (row & 7);
      gload_lds16(Kp + ((size_t)bh * S_ + kt * 64 + row) * 64 + cs * 8,
                  (char*)Ks + (w * 2 + i) * 1024);
      gload_lds16(Vt + ((size_t)bh * 64 + row) * S_ + kt * 64 + cs * 8,
                  (char*)Vs + (w * 2 + i) * 1024);
    }
    __syncthreads();

    // S = Q K^T (Q pre-scaled by 1/8)
    f32x4 s[2][4] = {};
#pragma unroll
    for (int ks = 0; ks < 2; ks++) {
      bf16x8 kf[4];
#pragma unroll
      for (int kb = 0; kb < 4; kb++) {
        int row = kb * 16 + l15;
        kf[kb] = *(const bf16x8*)((const char*)Ks + row * 128 +
                                  (((ks * 4 + l4) ^ (row & 7)) << 4));
      }
#pragma unroll
      for (int qb = 0; qb < 2; qb++)
#pragma unroll
        for (int kb = 0; kb < 4; kb++)
          s[qb][kb] = __builtin_amdgcn_mfma_f32_16x16x32_bf16(qf[qb][ks], kf[kb],
                                                              s[qb][kb], 0, 0, 0);
    }

    if (hz) {  // general masked path (not taken for all-ones mask)
#pragma unroll
      for (int qb = 0; qb < 2; qb++)
#pragma unroll
        for (int kb = 0; kb < 4; kb++)
#pragma unroll
          for (int r = 0; r < 4; r++) {
            int q = q0 + qb * 16 + l4 * 4 + r;
            int kc = kt * 64 + kb * 16 + l15;
            if (mask[((size_t)b * S_ + q) * S_ + kc] == 0) s[qb][kb][r] = -1e9f;
          }
    }

    // online softmax; C/D layout: col=lane&15 (k), row=(lane>>4)*4+reg (q)
#pragma unroll
    for (int qb = 0; qb < 2; qb++) {
      float alpha[4];
#pragma unroll
      for (int r = 0; r < 4; r++) {
        float v = fmaxf(fmaxf(s[qb][0][r], s[qb][1][r]),
                        fmaxf(s[qb][2][r], s[qb][3][r]));
        v = fmaxf(v, __shfl_xor(v, 1));
        v = fmaxf(v, __shfl_xor(v, 2));
        v = fmaxf(v, __shfl_xor(v, 4));
        v = fmaxf(v, __shfl_xor(v, 8));
        int idx = qb * 4 + r;
        float mo = mstate[idx];
        float mn = fmaxf(mo, v);
        float al = __expf(mo - mn);
        mstate[idx] = mn;
        alpha[r] = al;
        lstate[idx] *= al;
      }
      float rs[4] = {0.f, 0.f, 0.f, 0.f};
#pragma unroll
      for (int kb = 0; kb < 4; kb++)
#pragma unroll
        for (int r = 0; r < 4; r++) {
          float p = __expf(s[qb][kb][r] - mstate[qb * 4 + r]);
          s[qb][kb][r] = p;
          rs[r] += p;
        }
#pragma unroll
      for (int r = 0; r < 4; r++) {
        float v = rs[r];
        v += __shfl_xor(v, 1);
        v += __shfl_xor(v, 2);
        v += __shfl_xor(v, 4);
        v += __shfl_xor(v, 8);
        lstate[qb * 4 + r] += v;
      }
#pragma unroll
      for (int db = 0; db < 4; db++)
#pragma unroll
        for (int r = 0; r < 4; r++) accO[qb][db][r] *= alpha[r];
      // P -> LDS (bf16) for PV A-fragments
#pragma unroll
      for (int kb = 0; kb < 4; kb++)
#pragma unroll
        for (int r = 0; r < 4; r++)
          Pl[w][qb * 16 + l4 * 4 + r][kb * 16 + l15] = f2bf(s[qb][kb][r]);
    }
    __syncthreads();  // orders P writes before cross-lane reads (and Ks reads done)

    // O += P V : A = P rows (q), B = Vt rows (d), k = kpos
#pragma unroll
    for (int ks = 0; ks < 2; ks++) {
      bf16x8 pa[2], vf[4];
#pragma unroll
      for (int qb = 0; qb < 2; qb++)
        pa[qb] = *(const bf16x8*)((const char*)&Pl[w][qb * 16 + l15][0] +
                                  ks * 64 + l4 * 16);
#pragma unroll
      for (int db = 0; db < 4; db++) {
        int row = db * 16 + l15;
        vf[db] = *(const bf16x8*)((const char*)Vs + row * 128 +
                                  (((ks * 4 + l4) ^ (row & 7)) << 4));
      }
#pragma unroll
      for (int qb = 0; qb < 2; qb++)
#pragma unroll
        for (int db = 0; db < 4; db++)
          accO[qb][db] = __builtin_amdgcn_mfma_f32_16x16x32_bf16(pa[qb], vf[db],
                                                                 accO[qb][db], 0, 0, 0);
    }
    __syncthreads();  // Vs reads done before next tile's staging
  }

  // finalize: O /= l, store x[b,s,h*64+d] bf16
#pragma unroll
  for (int qb = 0; qb < 2; qb++)
#pragma unroll
    for (int db = 0; db < 4; db++)
#pragma unroll
      for (int r = 0; r < 4; r++) {
        float v = accO[qb][db][r] / lstate[qb * 4 + r];
        int q = q0 + qb * 16 + l4 * 4 + r;
        Xo[(((size_t)(b * S_ + q)) << 10) + h * 64 + db * 16 + l15] = f2bf(v);
      }
}

extern "C" void kernel_launch(void* const* d_in, const int* in_sizes, int n_in,
                              void* d_out, int out_size, void* d_ws, size_t ws_size,
                              hipStream_t stream) {
  const float* q = (const float*)d_in[0];
  const float* k = (const float*)d_in[1];
  const float* v = (const float*)d_in[2];
  const int* mask = (const int*)d_in[3];
  const float* Wq = (const float*)d_in[4];
  const float* Wk = (const float*)d_in[5];
  const float* Wv = (const float*)d_in[6];
  const float* Wo = (const float*)d_in[7];

  char* ws = (char*)d_ws;
  const size_t MB = 1024 * 1024;
  unsigned short* qb16 = (unsigned short*)(ws);            // 8 MB (reused as Xo)
  unsigned short* kb16 = (unsigned short*)(ws + 8 * MB);   // 8 MB
  unsigned short* vb16 = (unsigned short*)(ws + 16 * MB);  // 8 MB
  unsigned short* Wq16 = (unsigned short*)(ws + 24 * MB);  // 2 MB
  unsigned short* Wk16 = (unsigned short*)(ws + 26 * MB);
  unsigned short* Wv16 = (unsigned short*)(ws + 28 * MB);
  unsigned short* Wo16 = (unsigned short*)(ws + 30 * MB);
  unsigned short* Qp = (unsigned short*)(ws + 32 * MB);    // 8 MB [B,H,S,64]
  unsigned short* Kp = (unsigned short*)(ws + 40 * MB);    // 8 MB [B,H,S,64]
  unsigned short* Vtp = (unsigned short*)(ws + 48 * MB);   // 8 MB [B,H,64,S]
  int* flag = (int*)(ws + 56 * MB);
  unsigned short* Xo = qb16;  // alias: qb16 dead after gemm_qkv

  hipMemsetAsync(flag, 0, 4, stream);
  cvt_qkv<<<dim3(1024, 1, 3), 256, 0, stream>>>(q, k, v, qb16, kb16, vb16,
                                                (B_ * S_ * D_) / 4);
  cvt_w<<<dim3(256, 1, 4), 256, 0, stream>>>(Wq, Wk, Wv, Wo, Wq16, Wk16, Wv16, Wo16,
                                             (D_ * D_) / 4);
  mask_check<<<dim3(2048), 256, 0, stream>>>(mask, flag, (B_ * S_ * S_) / 4);
  gemm_qkv<<<dim3(8, 32, 3), 256, 0, stream>>>(qb16, kb16, vb16, Wq16, Wk16, Wv16,
                                               Qp, Kp, Vtp);
  attn<<<dim3(16, 16, 2), 256, 0, stream>>>(Qp, Kp, Vtp, Xo, flag, mask);
  gemm_o<<<dim3(8, 32), 256, 0, stream>>>(Xo, Wo16, (float*)d_out);
}

// Round 3
// 173.297 us; speedup vs baseline: 1.1630x; 1.1630x over previous
//
#include <hip/hip_runtime.h>
#include <hip/hip_bf16.h>

#define B_ 2
#define S_ 2048
#define D_ 1024
#define H_ 16

typedef __bf16 bf16x8 __attribute__((ext_vector_type(8)));
typedef __bf16 bf16x4v __attribute__((ext_vector_type(4)));
typedef float f32x4 __attribute__((ext_vector_type(4)));

__device__ __forceinline__ float exp2fast(float x) {
  return __builtin_amdgcn_exp2f(x);  // v_exp_f32: D = 2^S0
}

__device__ __forceinline__ unsigned short f2bf(float f) {
  unsigned int u = __float_as_uint(f);
  u += 0x7fff + ((u >> 16) & 1);   // RNE
  return (unsigned short)(u >> 16);
}

__device__ __forceinline__ void gload_lds16(const void* g, void* l) {
  __builtin_amdgcn_global_load_lds(
      (const __attribute__((address_space(1))) void*)g,
      (__attribute__((address_space(3))) void*)l, 16, 0, 0);
}

// ---------------- fp32 -> bf16 conversion ----------------
__global__ __launch_bounds__(256) void cvt_qkv(
    const float* __restrict__ a, const float* __restrict__ b, const float* __restrict__ c,
    unsigned short* __restrict__ da, unsigned short* __restrict__ db,
    unsigned short* __restrict__ dc, int n4) {
  const int z = blockIdx.z;
  const float* s = z == 0 ? a : (z == 1 ? b : c);
  unsigned short* d = z == 0 ? da : (z == 1 ? db : dc);
  int stride = gridDim.x * blockDim.x;
  for (int i = blockIdx.x * blockDim.x + threadIdx.x; i < n4; i += stride) {
    float4 f = ((const float4*)s)[i];
    ushort4 o;
    o.x = f2bf(f.x); o.y = f2bf(f.y); o.z = f2bf(f.z); o.w = f2bf(f.w);
    ((ushort4*)d)[i] = o;
  }
}

__global__ __launch_bounds__(256) void cvt_w(
    const float* __restrict__ a, const float* __restrict__ b,
    const float* __restrict__ c, const float* __restrict__ d,
    unsigned short* __restrict__ da, unsigned short* __restrict__ db,
    unsigned short* __restrict__ dc, unsigned short* __restrict__ dd, int n4) {
  const int z = blockIdx.z;
  const float* s = z == 0 ? a : (z == 1 ? b : (z == 2 ? c : d));
  unsigned short* o = z == 0 ? da : (z == 1 ? db : (z == 2 ? dc : dd));
  int stride = gridDim.x * blockDim.x;
  for (int i = blockIdx.x * blockDim.x + threadIdx.x; i < n4; i += stride) {
    float4 f = ((const float4*)s)[i];
    ushort4 u;
    u.x = f2bf(f.x); u.y = f2bf(f.y); u.z = f2bf(f.z); u.w = f2bf(f.w);
    ((ushort4*)o)[i] = u;
  }
}

// ---------------- mask all-ones check ----------------
__global__ __launch_bounds__(256) void mask_check(const int* __restrict__ m,
                                                  int* __restrict__ flag, int n4) {
  int stride = gridDim.x * blockDim.x;
  bool z = false;
  for (int i = blockIdx.x * blockDim.x + threadIdx.x; i < n4; i += stride) {
    int4 v = ((const int4*)m)[i];
    z |= (v.x == 0) || (v.y == 0) || (v.z == 0) || (v.w == 0);
  }
  if (__any(z)) {
    if ((threadIdx.x & 63) == 0) atomicOr(flag, 1);
  }
}

// ---------------- 128x128 bf16 GEMM core (m97 structure) ----------------
// y[i][n] = sum_k A[i][k] * W[n][k]  (NT: W row-major [N][K] is B^T)
__device__ __forceinline__ void gemm_core(
    const unsigned short* __restrict__ A, const unsigned short* __restrict__ W,
    unsigned short* As, unsigned short* Bs, int rowBase, int colBase,
    f32x4 (&acc)[4][4]) {
  const int tid = threadIdx.x, lane = tid & 63, w = tid >> 6;
  const int wm = w >> 1, wn = w & 1, l15 = lane & 15, l4 = lane >> 4;
  for (int kt = 0; kt < 16; ++kt) {
    // stage A[128][64], B[128][64] via global_load_lds, XOR-swizzled source
#pragma unroll
    for (int i = 0; i < 4; i++) {
      int chunk = (w * 4 + i) * 64 + lane;
      int row = chunk >> 3, c = chunk & 7;
      int cs = c ^ (row & 7);
      gload_lds16(A + (size_t)(rowBase + row) * 1024 + kt * 64 + cs * 8,
                  (char*)As + (w * 4 + i) * 1024);
      gload_lds16(W + (size_t)(colBase + row) * 1024 + kt * 64 + cs * 8,
                  (char*)Bs + (w * 4 + i) * 1024);
    }
    __syncthreads();
#pragma unroll
    for (int ks = 0; ks < 2; ks++) {
      bf16x8 af[4], bfr[4];
#pragma unroll
      for (int mi = 0; mi < 4; mi++) {
        int row = wm * 64 + mi * 16 + l15;
        af[mi] = *(const bf16x8*)((const char*)As + row * 128 +
                                  (((ks * 4 + l4) ^ (row & 7)) << 4));
      }
#pragma unroll
      for (int ni = 0; ni < 4; ni++) {
        int row = wn * 64 + ni * 16 + l15;
        bfr[ni] = *(const bf16x8*)((const char*)Bs + row * 128 +
                                   (((ks * 4 + l4) ^ (row & 7)) << 4));
      }
#pragma unroll
      for (int mi = 0; mi < 4; mi++)
#pragma unroll
        for (int ni = 0; ni < 4; ni++)
          acc[mi][ni] = __builtin_amdgcn_mfma_f32_16x16x32_bf16(
              af[mi], bfr[ni], acc[mi][ni], 0, 0, 0);
    }
    __syncthreads();
  }
}

// Q/K/V projections in one launch (grid.z selects).
// Q pre-scaled by 0.125*log2(e) so attention softmax runs in exp2 domain.
// Q,K stored [B,H,S,64]; V stored transposed [B,H,64,S].
__global__ __launch_bounds__(256, 2) void gemm_qkv(
    const unsigned short* __restrict__ qA, const unsigned short* __restrict__ kA,
    const unsigned short* __restrict__ vA,
    const unsigned short* __restrict__ Wq, const unsigned short* __restrict__ Wk,
    const unsigned short* __restrict__ Wv,
    unsigned short* __restrict__ Qp, unsigned short* __restrict__ Kp,
    unsigned short* __restrict__ Vtp) {
  __shared__ unsigned short As[128 * 64], Bs[128 * 64];
  const int z = blockIdx.z;
  const unsigned short* A = z == 0 ? qA : (z == 1 ? kA : vA);
  const unsigned short* W = z == 0 ? Wq : (z == 1 ? Wk : Wv);
  const int rowBase = blockIdx.y * 128, colBase = blockIdx.x * 128;
  f32x4 acc[4][4] = {};
  gemm_core(A, W, As, Bs, rowBase, colBase, acc);
  const int tid = threadIdx.x, lane = tid & 63, w = tid >> 6;
  const int wm = w >> 1, wn = w & 1, l15 = lane & 15, l4 = lane >> 4;
#pragma unroll
  for (int mi = 0; mi < 4; mi++)
#pragma unroll
    for (int ni = 0; ni < 4; ni++)
#pragma unroll
      for (int r = 0; r < 4; r++) {
        int gr = rowBase + wm * 64 + mi * 16 + l4 * 4 + r;  // b*S + s
        int gc = colBase + wn * 64 + ni * 16 + l15;         // h*64 + d
        int b = gr >> 11, s = gr & 2047, h = gc >> 6, d = gc & 63;
        float v = acc[mi][ni][r];
        if (z == 0)
          Qp[(((size_t)(b * 16 + h) * 2048 + s) << 6) + d] =
              f2bf(v * 0.18033688011112042f);  // 0.125 * log2(e)
        else if (z == 1)
          Kp[(((size_t)(b * 16 + h) * 2048 + s) << 6) + d] = f2bf(v);
        else
          Vtp[((size_t)(b * 16 + h) * 64 + d) * 2048 + s] = f2bf(v);
      }
}

// Output projection -> fp32 d_out
__global__ __launch_bounds__(256, 2) void gemm_o(
    const unsigned short* __restrict__ A, const unsigned short* __restrict__ W,
    float* __restrict__ Out) {
  __shared__ unsigned short As[128 * 64], Bs[128 * 64];
  const int rowBase = blockIdx.y * 128, colBase = blockIdx.x * 128;
  f32x4 acc[4][4] = {};
  gemm_core(A, W, As, Bs, rowBase, colBase, acc);
  const int tid = threadIdx.x, lane = tid & 63, w = tid >> 6;
  const int wm = w >> 1, wn = w & 1, l15 = lane & 15, l4 = lane >> 4;
#pragma unroll
  for (int mi = 0; mi < 4; mi++)
#pragma unroll
    for (int ni = 0; ni < 4; ni++)
#pragma unroll
      for (int r = 0; r < 4; r++) {
        int gr = rowBase + wm * 64 + mi * 16 + l4 * 4 + r;
        int gc = colBase + wn * 64 + ni * 16 + l15;
        Out[(size_t)gr * 1024 + gc] = acc[mi][ni][r];
      }
}

// ---------------- flash attention (swapped-operand, per-lane softmax) ---------
// grid (S/64, H, B), 256 threads = 4 waves, wave owns 16 q rows (q = q0+l15).
// QK^T computed as mfma(K, Q^T): C col = q = lane&15, row = kpos.
// PV   computed as mfma(Vt, P^T): C col = q = lane&15, row = d.
// => running m/l are per-lane scalars (replicated over the 4 l4-groups).
__global__ __launch_bounds__(256, 3) void attn(
    const unsigned short* __restrict__ Qp, const unsigned short* __restrict__ Kp,
    const unsigned short* __restrict__ Vt, unsigned short* __restrict__ Xo,
    const int* __restrict__ flag, const int* __restrict__ mask) {
  __shared__ unsigned short Ks[2][64 * 64];  // double-buffered [kpos][d]
  __shared__ unsigned short Vs[2][64 * 64];  // double-buffered [d][kpos]
  __shared__ unsigned short Pl[4][16][72];   // per-wave P[q][kpos], pad 64->72
  const int tid = threadIdx.x, lane = tid & 63, w = tid >> 6;
  const int l15 = lane & 15, l4 = lane >> 4;
  const int h = blockIdx.y, b = blockIdx.z;
  const int bh = b * H_ + h;
  const int q0 = blockIdx.x * 64 + w * 16;
  const int hz = *flag;

  bf16x8 qf[2];
#pragma unroll
  for (int ks = 0; ks < 2; ks++)
    qf[ks] = *(const bf16x8*)(Qp + ((size_t)bh * S_ + q0 + l15) * 64 +
                              ks * 32 + l4 * 8);

  float m = -__builtin_inff(), l = 0.f;
  f32x4 accOT[4] = {};  // [db]: col=q=l15, row=d=db*16+l4*4+r

  auto stage = [&](int kt, int buf) {
#pragma unroll
    for (int i = 0; i < 2; i++) {
      int ch = (w * 2 + i) * 64 + lane;
      int row = ch >> 3, c = ch & 7;
      int cs = c ^ (row & 7);
      gload_lds16(Kp + ((size_t)bh * S_ + kt * 64 + row) * 64 + cs * 8,
                  (char*)&Ks[buf][0] + (w * 2 + i) * 1024);
      gload_lds16(Vt + ((size_t)bh * 64 + row) * S_ + kt * 64 + cs * 8,
                  (char*)&Vs[buf][0] + (w * 2 + i) * 1024);
    }
  };

  stage(0, 0);
  __syncthreads();

  for (int kt = 0; kt < 32; ++kt) {
    const int cur = kt & 1;
    if (kt < 31) stage(kt + 1, cur ^ 1);  // prefetch flies under compute

    // S^T tile: s[kb] holds S[kpos = kb*16 + l4*4 + r][q = l15] (log2e-scaled)
    f32x4 s[4] = {};
#pragma unroll
    for (int ks = 0; ks < 2; ks++) {
      bf16x8 kf[4];
#pragma unroll
      for (int kb = 0; kb < 4; kb++) {
        int row = kb * 16 + l15;
        kf[kb] = *(const bf16x8*)((const char*)&Ks[cur][0] + row * 128 +
                                  (((ks * 4 + l4) ^ (row & 7)) << 4));
      }
#pragma unroll
      for (int kb = 0; kb < 4; kb++)
        s[kb] = __builtin_amdgcn_mfma_f32_16x16x32_bf16(kf[kb], qf[ks],
                                                        s[kb], 0, 0, 0);
    }

    if (hz) {  // general masked path (not taken for all-ones mask)
#pragma unroll
      for (int kb = 0; kb < 4; kb++)
#pragma unroll
        for (int r = 0; r < 4; r++) {
          int kc = kt * 64 + kb * 16 + l4 * 4 + r;
          if (mask[((size_t)b * S_ + q0 + l15) * S_ + kc] == 0) s[kb][r] = -1e9f;
        }
    }

    // per-lane online softmax (q = l15), exp2 domain
    float m0 = fmaxf(fmaxf(s[0][0], s[0][1]), fmaxf(s[0][2], s[0][3]));
    float m1 = fmaxf(fmaxf(s[1][0], s[1][1]), fmaxf(s[1][2], s[1][3]));
    float m2 = fmaxf(fmaxf(s[2][0], s[2][1]), fmaxf(s[2][2], s[2][3]));
    float m3 = fmaxf(fmaxf(s[3][0], s[3][1]), fmaxf(s[3][2], s[3][3]));
    float mx = fmaxf(fmaxf(m0, m1), fmaxf(m2, m3));
    mx = fmaxf(mx, __shfl_xor(mx, 16));
    mx = fmaxf(mx, __shfl_xor(mx, 32));

    if (!__all(mx - m <= 8.f)) {  // defer-max: skip rescale when growth small
      float mn = fmaxf(m, mx);
      float al = exp2fast(m - mn);
      m = mn;
      l *= al;
#pragma unroll
      for (int db = 0; db < 4; db++) accOT[db] *= al;
    }

    float rs = 0.f;
#pragma unroll
    for (int kb = 0; kb < 4; kb++) {
      bf16x4v pk;
#pragma unroll
      for (int r = 0; r < 4; r++) {
        float p = exp2fast(s[kb][r] - m);
        rs += p;
        pk[r] = (__bf16)p;
      }
      // lane holds 4 consecutive kpos per kb -> one 8B write
      *(bf16x4v*)(&Pl[w][l15][kb * 16 + l4 * 4]) = pk;
    }
    rs += __shfl_xor(rs, 16);
    rs += __shfl_xor(rs, 32);
    l += rs;

    // O^T += V^T P^T  (wave-private Pl: no barrier needed before reads)
#pragma unroll
    for (int ks = 0; ks < 2; ks++) {
      bf16x8 pa = *(const bf16x8*)((const char*)&Pl[w][l15][0] + ks * 64 + l4 * 16);
      bf16x8 vf[4];
#pragma unroll
      for (int db = 0; db < 4; db++) {
        int row = db * 16 + l15;
        vf[db] = *(const bf16x8*)((const char*)&Vs[cur][0] + row * 128 +
                                  (((ks * 4 + l4) ^ (row & 7)) << 4));
      }
#pragma unroll
      for (int db = 0; db < 4; db++)
        accOT[db] = __builtin_amdgcn_mfma_f32_16x16x32_bf16(vf[db], pa,
                                                            accOT[db], 0, 0, 0);
    }
    __syncthreads();  // one barrier/tile: reads done + prefetch (vmcnt) drained
  }

  // finalize: O /= l; store x[b, q, h*64 + d] bf16 (4 consecutive d per store)
  float rl = 1.0f / l;
  const int q = q0 + l15;
#pragma unroll
  for (int db = 0; db < 4; db++) {
    bf16x4v o;
#pragma unroll
    for (int r = 0; r < 4; r++) o[r] = (__bf16)(accOT[db][r] * rl);
    *(bf16x4v*)(Xo + (((size_t)(b * S_ + q)) << 10) + h * 64 + db * 16 + l4 * 4) = o;
  }
}

extern "C" void kernel_launch(void* const* d_in, const int* in_sizes, int n_in,
                              void* d_out, int out_size, void* d_ws, size_t ws_size,
                              hipStream_t stream) {
  const float* q = (const float*)d_in[0];
  const float* k = (const float*)d_in[1];
  const float* v = (const float*)d_in[2];
  const int* mask = (const int*)d_in[3];
  const float* Wq = (const float*)d_in[4];
  const float* Wk = (const float*)d_in[5];
  const float* Wv = (const float*)d_in[6];
  const float* Wo = (const float*)d_in[7];

  char* ws = (char*)d_ws;
  const size_t MB = 1024 * 1024;
  unsigned short* qb16 = (unsigned short*)(ws);            // 8 MB (reused as Xo)
  unsigned short* kb16 = (unsigned short*)(ws + 8 * MB);   // 8 MB
  unsigned short* vb16 = (unsigned short*)(ws + 16 * MB);  // 8 MB
  unsigned short* Wq16 = (unsigned short*)(ws + 24 * MB);  // 2 MB
  unsigned short* Wk16 = (unsigned short*)(ws + 26 * MB);
  unsigned short* Wv16 = (unsigned short*)(ws + 28 * MB);
  unsigned short* Wo16 = (unsigned short*)(ws + 30 * MB);
  unsigned short* Qp = (unsigned short*)(ws + 32 * MB);    // 8 MB [B,H,S,64]
  unsigned short* Kp = (unsigned short*)(ws + 40 * MB);    // 8 MB [B,H,S,64]
  unsigned short* Vtp = (unsigned short*)(ws + 48 * MB);   // 8 MB [B,H,64,S]
  int* flag = (int*)(ws + 56 * MB);
  unsigned short* Xo = qb16;  // alias: qb16 dead after gemm_qkv

  (void)hipMemsetAsync(flag, 0, 4, stream);
  cvt_qkv<<<dim3(1024, 1, 3), 256, 0, stream>>>(q, k, v, qb16, kb16, vb16,
                                                (B_ * S_ * D_) / 4);
  cvt_w<<<dim3(256, 1, 4), 256, 0, stream>>>(Wq, Wk, Wv, Wo, Wq16, Wk16, Wv16, Wo16,
                                             (D_ * D_) / 4);
  mask_check<<<dim3(2048), 256, 0, stream>>>(mask, flag, (B_ * S_ * S_) / 4);
  gemm_qkv<<<dim3(8, 32, 3), 256, 0, stream>>>(qb16, kb16, vb16, Wq16, Wk16, Wv16,
                                               Qp, Kp, Vtp);
  attn<<<dim3(32, 16, 2), 256, 0, stream>>>(Qp, Kp, Vtp, Xo, flag, mask);
  gemm_o<<<dim3(8, 32), 256, 0, stream>>>(Xo, Wo16, (float*)d_out);
}

// Round 4
// 158.322 us; speedup vs baseline: 1.2730x; 1.0946x over previous
//
#include <hip/hip_runtime.h>
#include <hip/hip_bf16.h>

#define B_ 2
#define S_ 2048
#define D_ 1024
#define H_ 16

typedef __bf16 bf16x8 __attribute__((ext_vector_type(8)));
typedef __bf16 bf16x4v __attribute__((ext_vector_type(4)));
typedef float f32x4 __attribute__((ext_vector_type(4)));

__device__ __forceinline__ float exp2fast(float x) {
  return __builtin_amdgcn_exp2f(x);  // v_exp_f32: D = 2^S0
}

__device__ __forceinline__ unsigned short f2bf(float f) {
  unsigned int u = __float_as_uint(f);
  u += 0x7fff + ((u >> 16) & 1);   // RNE
  return (unsigned short)(u >> 16);
}

__device__ __forceinline__ void gload_lds16(const void* g, void* l) {
  __builtin_amdgcn_global_load_lds(
      (const __attribute__((address_space(1))) void*)g,
      (__attribute__((address_space(3))) void*)l, 16, 0, 0);
}

// ---------------- fp32 -> bf16 conversion ----------------
__global__ __launch_bounds__(256) void cvt_qkv(
    const float* __restrict__ a, const float* __restrict__ b, const float* __restrict__ c,
    unsigned short* __restrict__ da, unsigned short* __restrict__ db,
    unsigned short* __restrict__ dc, int n4) {
  const int z = blockIdx.z;
  const float* s = z == 0 ? a : (z == 1 ? b : c);
  unsigned short* d = z == 0 ? da : (z == 1 ? db : dc);
  int stride = gridDim.x * blockDim.x;
  for (int i = blockIdx.x * blockDim.x + threadIdx.x; i < n4; i += stride) {
    float4 f = ((const float4*)s)[i];
    ushort4 o;
    o.x = f2bf(f.x); o.y = f2bf(f.y); o.z = f2bf(f.z); o.w = f2bf(f.w);
    ((ushort4*)d)[i] = o;
  }
}

__global__ __launch_bounds__(256) void cvt_w(
    const float* __restrict__ a, const float* __restrict__ b,
    const float* __restrict__ c, const float* __restrict__ d,
    unsigned short* __restrict__ da, unsigned short* __restrict__ db,
    unsigned short* __restrict__ dc, unsigned short* __restrict__ dd, int n4) {
  const int z = blockIdx.z;
  const float* s = z == 0 ? a : (z == 1 ? b : (z == 2 ? c : d));
  unsigned short* o = z == 0 ? da : (z == 1 ? db : (z == 2 ? dc : dd));
  int stride = gridDim.x * blockDim.x;
  for (int i = blockIdx.x * blockDim.x + threadIdx.x; i < n4; i += stride) {
    float4 f = ((const float4*)s)[i];
    ushort4 u;
    u.x = f2bf(f.x); u.y = f2bf(f.y); u.z = f2bf(f.z); u.w = f2bf(f.w);
    ((ushort4*)o)[i] = u;
  }
}

// ---------------- mask all-ones check ----------------
__global__ __launch_bounds__(256) void mask_check(const int* __restrict__ m,
                                                  int* __restrict__ flag, int n4) {
  int stride = gridDim.x * blockDim.x;
  bool z = false;
  for (int i = blockIdx.x * blockDim.x + threadIdx.x; i < n4; i += stride) {
    int4 v = ((const int4*)m)[i];
    z |= (v.x == 0) || (v.y == 0) || (v.z == 0) || (v.w == 0);
  }
  if (__any(z)) {
    if ((threadIdx.x & 63) == 0) atomicOr(flag, 1);
  }
}

// ---------------- 128x128 bf16 GEMM core (m97 structure) ----------------
// y[i][n] = sum_k A[i][k] * W[n][k]  (NT: W row-major [N][K] is B^T)
__device__ __forceinline__ void gemm_core(
    const unsigned short* __restrict__ A, const unsigned short* __restrict__ W,
    unsigned short* As, unsigned short* Bs, int rowBase, int colBase,
    f32x4 (&acc)[4][4]) {
  const int tid = threadIdx.x, lane = tid & 63, w = tid >> 6;
  const int wm = w >> 1, wn = w & 1, l15 = lane & 15, l4 = lane >> 4;
  for (int kt = 0; kt < 16; ++kt) {
    // stage A[128][64], B[128][64] via global_load_lds, XOR-swizzled source
#pragma unroll
    for (int i = 0; i < 4; i++) {
      int chunk = (w * 4 + i) * 64 + lane;
      int row = chunk >> 3, c = chunk & 7;
      int cs = c ^ (row & 7);
      gload_lds16(A + (size_t)(rowBase + row) * 1024 + kt * 64 + cs * 8,
                  (char*)As + (w * 4 + i) * 1024);
      gload_lds16(W + (size_t)(colBase + row) * 1024 + kt * 64 + cs * 8,
                  (char*)Bs + (w * 4 + i) * 1024);
    }
    __syncthreads();
#pragma unroll
    for (int ks = 0; ks < 2; ks++) {
      bf16x8 af[4], bfr[4];
#pragma unroll
      for (int mi = 0; mi < 4; mi++) {
        int row = wm * 64 + mi * 16 + l15;
        af[mi] = *(const bf16x8*)((const char*)As + row * 128 +
                                  (((ks * 4 + l4) ^ (row & 7)) << 4));
      }
#pragma unroll
      for (int ni = 0; ni < 4; ni++) {
        int row = wn * 64 + ni * 16 + l15;
        bfr[ni] = *(const bf16x8*)((const char*)Bs + row * 128 +
                                   (((ks * 4 + l4) ^ (row & 7)) << 4));
      }
#pragma unroll
      for (int mi = 0; mi < 4; mi++)
#pragma unroll
        for (int ni = 0; ni < 4; ni++)
          acc[mi][ni] = __builtin_amdgcn_mfma_f32_16x16x32_bf16(
              af[mi], bfr[ni], acc[mi][ni], 0, 0, 0);
    }
    __syncthreads();
  }
}

// Q/K/V projections in one launch (grid.z selects).
// Q pre-scaled by 0.125*log2(e) so attention softmax runs in exp2 domain.
// Q,K stored [B,H,S,64]; V stored transposed [B,H,64,S].
__global__ __launch_bounds__(256, 2) void gemm_qkv(
    const unsigned short* __restrict__ qA, const unsigned short* __restrict__ kA,
    const unsigned short* __restrict__ vA,
    const unsigned short* __restrict__ Wq, const unsigned short* __restrict__ Wk,
    const unsigned short* __restrict__ Wv,
    unsigned short* __restrict__ Qp, unsigned short* __restrict__ Kp,
    unsigned short* __restrict__ Vtp) {
  __shared__ unsigned short As[128 * 64], Bs[128 * 64];
  const int z = blockIdx.z;
  const unsigned short* A = z == 0 ? qA : (z == 1 ? kA : vA);
  const unsigned short* W = z == 0 ? Wq : (z == 1 ? Wk : Wv);
  const int rowBase = blockIdx.y * 128, colBase = blockIdx.x * 128;
  f32x4 acc[4][4] = {};
  gemm_core(A, W, As, Bs, rowBase, colBase, acc);
  const int tid = threadIdx.x, lane = tid & 63, w = tid >> 6;
  const int wm = w >> 1, wn = w & 1, l15 = lane & 15, l4 = lane >> 4;
#pragma unroll
  for (int mi = 0; mi < 4; mi++)
#pragma unroll
    for (int ni = 0; ni < 4; ni++)
#pragma unroll
      for (int r = 0; r < 4; r++) {
        int gr = rowBase + wm * 64 + mi * 16 + l4 * 4 + r;  // b*S + s
        int gc = colBase + wn * 64 + ni * 16 + l15;         // h*64 + d
        int b = gr >> 11, s = gr & 2047, h = gc >> 6, d = gc & 63;
        float v = acc[mi][ni][r];
        if (z == 0)
          Qp[(((size_t)(b * 16 + h) * 2048 + s) << 6) + d] =
              f2bf(v * 0.18033688011112042f);  // 0.125 * log2(e)
        else if (z == 1)
          Kp[(((size_t)(b * 16 + h) * 2048 + s) << 6) + d] = f2bf(v);
        else
          Vtp[((size_t)(b * 16 + h) * 64 + d) * 2048 + s] = f2bf(v);
      }
}

// Output projection -> fp32 d_out
__global__ __launch_bounds__(256, 2) void gemm_o(
    const unsigned short* __restrict__ A, const unsigned short* __restrict__ W,
    float* __restrict__ Out) {
  __shared__ unsigned short As[128 * 64], Bs[128 * 64];
  const int rowBase = blockIdx.y * 128, colBase = blockIdx.x * 128;
  f32x4 acc[4][4] = {};
  gemm_core(A, W, As, Bs, rowBase, colBase, acc);
  const int tid = threadIdx.x, lane = tid & 63, w = tid >> 6;
  const int wm = w >> 1, wn = w & 1, l15 = lane & 15, l4 = lane >> 4;
#pragma unroll
  for (int mi = 0; mi < 4; mi++)
#pragma unroll
    for (int ni = 0; ni < 4; ni++)
#pragma unroll
      for (int r = 0; r < 4; r++) {
        int gr = rowBase + wm * 64 + mi * 16 + l4 * 4 + r;
        int gc = colBase + wn * 64 + ni * 16 + l15;
        Out[(size_t)gr * 1024 + gc] = acc[mi][ni][r];
      }
}

// ---------------- flash attention (swapped-operand, per-lane softmax) ---------
// grid (S/128, H, B), 256 threads = 4 waves, wave owns 32 q rows (2 q-groups).
// QK^T computed as mfma(K, Q^T): C col = q = lane&15, row = kpos.
// PV   computed as mfma(Vt, P^T): C col = q = lane&15, row = d.
// K/V fragments are shared across the 2 q-groups: 2 MFMAs per fragment read.
__global__ __launch_bounds__(256, 2) void attn(
    const unsigned short* __restrict__ Qp, const unsigned short* __restrict__ Kp,
    const unsigned short* __restrict__ Vt, unsigned short* __restrict__ Xo,
    const int* __restrict__ flag, const int* __restrict__ mask) {
  __shared__ unsigned short Ks[2][64 * 64];  // double-buffered [kpos][d]
  __shared__ unsigned short Vs[2][64 * 64];  // double-buffered [d][kpos]
  __shared__ unsigned short Pl[4][32][72];   // per-wave P[q][kpos], pad 64->72
  const int tid = threadIdx.x, lane = tid & 63, w = tid >> 6;
  const int l15 = lane & 15, l4 = lane >> 4;
  const int h = blockIdx.y, b = blockIdx.z;
  const int bh = b * H_ + h;
  const int q0 = blockIdx.x * 128 + w * 32;
  const int hz = *flag;

  bf16x8 qf[2][2];
#pragma unroll
  for (int qg = 0; qg < 2; qg++)
#pragma unroll
    for (int ks = 0; ks < 2; ks++)
      qf[qg][ks] = *(const bf16x8*)(Qp + ((size_t)bh * S_ + q0 + qg * 16 + l15) * 64 +
                                    ks * 32 + l4 * 8);

  float m[2] = {-__builtin_inff(), -__builtin_inff()};
  float l[2] = {0.f, 0.f};
  f32x4 accOT[2][4] = {};  // [qg][db]: col=q=l15, row=d=db*16+l4*4+r

  auto stage = [&](int kt, int buf) {
#pragma unroll
    for (int i = 0; i < 2; i++) {
      int ch = (w * 2 + i) * 64 + lane;
      int row = ch >> 3, c = ch & 7;
      int cs = c ^ (row & 7);
      gload_lds16(Kp + ((size_t)bh * S_ + kt * 64 + row) * 64 + cs * 8,
                  (char*)&Ks[buf][0] + (w * 2 + i) * 1024);
      gload_lds16(Vt + ((size_t)bh * 64 + row) * S_ + kt * 64 + cs * 8,
                  (char*)&Vs[buf][0] + (w * 2 + i) * 1024);
    }
  };

  stage(0, 0);
  __syncthreads();

  for (int kt = 0; kt < 32; ++kt) {
    const int cur = kt & 1;
    if (kt < 31) stage(kt + 1, cur ^ 1);  // prefetch flies under compute

    // S^T tiles: s[qg][kb] holds S[kpos = kb*16+l4*4+r][q = qg*16+l15]
    f32x4 s[2][4] = {};
#pragma unroll
    for (int ks = 0; ks < 2; ks++) {
      bf16x8 kf[4];
#pragma unroll
      for (int kb = 0; kb < 4; kb++) {
        int row = kb * 16 + l15;
        kf[kb] = *(const bf16x8*)((const char*)&Ks[cur][0] + row * 128 +
                                  (((ks * 4 + l4) ^ (row & 7)) << 4));
      }
#pragma unroll
      for (int qg = 0; qg < 2; qg++)
#pragma unroll
        for (int kb = 0; kb < 4; kb++)
          s[qg][kb] = __builtin_amdgcn_mfma_f32_16x16x32_bf16(kf[kb], qf[qg][ks],
                                                              s[qg][kb], 0, 0, 0);
    }

    if (hz) {  // general masked path (not taken for all-ones mask)
#pragma unroll
      for (int qg = 0; qg < 2; qg++)
#pragma unroll
        for (int kb = 0; kb < 4; kb++)
#pragma unroll
          for (int r = 0; r < 4; r++) {
            int kc = kt * 64 + kb * 16 + l4 * 4 + r;
            if (mask[((size_t)b * S_ + q0 + qg * 16 + l15) * S_ + kc] == 0)
              s[qg][kb][r] = -1e9f;
          }
    }

    // per-lane online softmax (q = qg*16+l15), exp2 domain
    float mx[2];
#pragma unroll
    for (int qg = 0; qg < 2; qg++) {
      float m0 = fmaxf(fmaxf(s[qg][0][0], s[qg][0][1]), fmaxf(s[qg][0][2], s[qg][0][3]));
      float m1 = fmaxf(fmaxf(s[qg][1][0], s[qg][1][1]), fmaxf(s[qg][1][2], s[qg][1][3]));
      float m2 = fmaxf(fmaxf(s[qg][2][0], s[qg][2][1]), fmaxf(s[qg][2][2], s[qg][2][3]));
      float m3 = fmaxf(fmaxf(s[qg][3][0], s[qg][3][1]), fmaxf(s[qg][3][2], s[qg][3][3]));
      float v = fmaxf(fmaxf(m0, m1), fmaxf(m2, m3));
      v = fmaxf(v, __shfl_xor(v, 16));
      v = fmaxf(v, __shfl_xor(v, 32));
      mx[qg] = v;
    }

    if (!__all(mx[0] - m[0] <= 8.f && mx[1] - m[1] <= 8.f)) {  // defer-max
#pragma unroll
      for (int qg = 0; qg < 2; qg++) {
        float mn = fmaxf(m[qg], mx[qg]);
        float al = exp2fast(m[qg] - mn);
        m[qg] = mn;
        l[qg] *= al;
#pragma unroll
        for (int db = 0; db < 4; db++) accOT[qg][db] *= al;
      }
    }

#pragma unroll
    for (int qg = 0; qg < 2; qg++) {
      float rs = 0.f;
#pragma unroll
      for (int kb = 0; kb < 4; kb++) {
        bf16x4v pk;
#pragma unroll
        for (int r = 0; r < 4; r++) {
          float p = exp2fast(s[qg][kb][r] - m[qg]);
          rs += p;
          pk[r] = (__bf16)p;
        }
        *(bf16x4v*)(&Pl[w][qg * 16 + l15][kb * 16 + l4 * 4]) = pk;
      }
      rs += __shfl_xor(rs, 16);
      rs += __shfl_xor(rs, 32);
      l[qg] += rs;
    }

    // O^T += V^T P^T  (wave-private Pl: no barrier needed before reads)
#pragma unroll
    for (int ks = 0; ks < 2; ks++) {
      bf16x8 vf[4], pa[2];
#pragma unroll
      for (int qg = 0; qg < 2; qg++)
        pa[qg] = *(const bf16x8*)((const char*)&Pl[w][qg * 16 + l15][0] +
                                  ks * 64 + l4 * 16);
#pragma unroll
      for (int db = 0; db < 4; db++) {
        int row = db * 16 + l15;
        vf[db] = *(const bf16x8*)((const char*)&Vs[cur][0] + row * 128 +
                                  (((ks * 4 + l4) ^ (row & 7)) << 4));
      }
#pragma unroll
      for (int qg = 0; qg < 2; qg++)
#pragma unroll
        for (int db = 0; db < 4; db++)
          accOT[qg][db] = __builtin_amdgcn_mfma_f32_16x16x32_bf16(vf[db], pa[qg],
                                                                  accOT[qg][db], 0, 0, 0);
    }
    __syncthreads();  // one barrier/tile: reads done + prefetch (vmcnt) drained
  }

  // finalize: O /= l; store x[b, q, h*64 + d] bf16 (4 consecutive d per store)
#pragma unroll
  for (int qg = 0; qg < 2; qg++) {
    float rl = 1.0f / l[qg];
    const int q = q0 + qg * 16 + l15;
#pragma unroll
    for (int db = 0; db < 4; db++) {
      bf16x4v o;
#pragma unroll
      for (int r = 0; r < 4; r++) o[r] = (__bf16)(accOT[qg][db][r] * rl);
      *(bf16x4v*)(Xo + (((size_t)(b * S_ + q)) << 10) + h * 64 + db * 16 + l4 * 4) = o;
    }
  }
}

extern "C" void kernel_launch(void* const* d_in, const int* in_sizes, int n_in,
                              void* d_out, int out_size, void* d_ws, size_t ws_size,
                              hipStream_t stream) {
  const float* q = (const float*)d_in[0];
  const float* k = (const float*)d_in[1];
  const float* v = (const float*)d_in[2];
  const int* mask = (const int*)d_in[3];
  const float* Wq = (const float*)d_in[4];
  const float* Wk = (const float*)d_in[5];
  const float* Wv = (const float*)d_in[6];
  const float* Wo = (const float*)d_in[7];

  char* ws = (char*)d_ws;
  const size_t MB = 1024 * 1024;
  unsigned short* qb16 = (unsigned short*)(ws);            // 8 MB (reused as Xo)
  unsigned short* kb16 = (unsigned short*)(ws + 8 * MB);   // 8 MB
  unsigned short* vb16 = (unsigned short*)(ws + 16 * MB);  // 8 MB
  unsigned short* Wq16 = (unsigned short*)(ws + 24 * MB);  // 2 MB
  unsigned short* Wk16 = (unsigned short*)(ws + 26 * MB);
  unsigned short* Wv16 = (unsigned short*)(ws + 28 * MB);
  unsigned short* Wo16 = (unsigned short*)(ws + 30 * MB);
  unsigned short* Qp = (unsigned short*)(ws + 32 * MB);    // 8 MB [B,H,S,64]
  unsigned short* Kp = (unsigned short*)(ws + 40 * MB);    // 8 MB [B,H,S,64]
  unsigned short* Vtp = (unsigned short*)(ws + 48 * MB);   // 8 MB [B,H,64,S]
  int* flag = (int*)(ws + 56 * MB);
  unsigned short* Xo = qb16;  // alias: qb16 dead after gemm_qkv

  (void)hipMemsetAsync(flag, 0, 4, stream);
  cvt_qkv<<<dim3(1024, 1, 3), 256, 0, stream>>>(q, k, v, qb16, kb16, vb16,
                                                (B_ * S_ * D_) / 4);
  cvt_w<<<dim3(256, 1, 4), 256, 0, stream>>>(Wq, Wk, Wv, Wo, Wq16, Wk16, Wv16, Wo16,
                                             (D_ * D_) / 4);
  mask_check<<<dim3(2048), 256, 0, stream>>>(mask, flag, (B_ * S_ * S_) / 4);
  gemm_qkv<<<dim3(8, 32, 3), 256, 0, stream>>>(qb16, kb16, vb16, Wq16, Wk16, Wv16,
                                               Qp, Kp, Vtp);
  attn<<<dim3(16, 16, 2), 256, 0, stream>>>(Qp, Kp, Vtp, Xo, flag, mask);
  gemm_o<<<dim3(8, 32), 256, 0, stream>>>(Xo, Wo16, (float*)d_out);
}